// Round 1
// baseline (299.255 us; speedup 1.0000x reference)
//
#include <hip/hip_runtime.h>
#include <stdint.h>

#define N_NODES 10000
#define N_EDGES 320000
#define D_IN    512
#define D_HID   2048
#define N_CLS   40
#define MP1     10112   // 79*128  (GEMM1 M padding)

typedef float f32x4  __attribute__((ext_vector_type(4)));
typedef short bf16x8 __attribute__((ext_vector_type(8)));
typedef unsigned short us4 __attribute__((ext_vector_type(4)));

__device__ inline unsigned short f2bf(float f){
  unsigned int u = __float_as_uint(f);
  u += 0x7fffu + ((u >> 16) & 1u);   // round-to-nearest-even
  return (unsigned short)(u >> 16);
}

__device__ inline void gl_lds16(const void* g, void* l){
  __builtin_amdgcn_global_load_lds((const __attribute__((address_space(1))) void*)g,
                                   (__attribute__((address_space(3))) void*)l, 16, 0, 0);
}

// ---------------- graph preprocessing ----------------
__global__ void k_count(const int* __restrict__ ei, int* __restrict__ deg){
  int e = blockIdx.x*256 + threadIdx.x;
  if (e < N_EDGES) atomicAdd(&deg[ei[N_EDGES + e]], 1);
}

__global__ void k_dinv(const int* __restrict__ deg, float* __restrict__ dinv){
  int i = blockIdx.x*256 + threadIdx.x;
  if (i < N_NODES) dinv[i] = rsqrtf((float)deg[i] + 1.0f);
}

__global__ void k_scan(const int* __restrict__ deg, int* __restrict__ offsets, int* __restrict__ cursor){
  __shared__ int sums[1024];
  const int t = threadIdx.x;
  const int CH = 10;                       // 1024*10 >= 10000
  int base = t*CH;
  int local[CH]; int s = 0;
  for (int j = 0; j < CH; j++){
    int v = (base + j < N_NODES) ? deg[base + j] : 0;
    local[j] = s; s += v;
  }
  sums[t] = s;
  __syncthreads();
  for (int off = 1; off < 1024; off <<= 1){
    int v = (t >= off) ? sums[t - off] : 0;
    __syncthreads();
    sums[t] += v;
    __syncthreads();
  }
  int pre = (t > 0) ? sums[t-1] : 0;
  for (int j = 0; j < CH; j++){
    int idx = base + j;
    if (idx < N_NODES){ int o = pre + local[j]; offsets[idx] = o; cursor[idx] = o; }
  }
}

__global__ void k_fill(const int* __restrict__ ei, int* __restrict__ cursor, int* __restrict__ csr_src){
  int e = blockIdx.x*256 + threadIdx.x;
  if (e < N_EDGES){
    int s = ei[e], d = ei[N_EDGES + e];
    int pos = atomicAdd(&cursor[d], 1);
    csr_src[pos] = s;
  }
}

// ---------------- propagate(x) -> Pb (bf16) ----------------
__global__ void k_gather1(const float* __restrict__ x, const int* __restrict__ csr_src,
                          const int* __restrict__ offsets, const int* __restrict__ deg,
                          const float* __restrict__ dinv, unsigned short* __restrict__ Pb){
  __shared__ int   ssrc[128];
  __shared__ float scoef[128];
  const int i = blockIdx.x;
  const int t = threadIdx.x;             // 0..127, each owns float4 of the 512 features
  const float di = dinv[i];
  const f32x4* x4 = (const f32x4*)x;
  f32x4 acc = (di*di) * x4[i*128 + t];   // self loop
  const int start = offsets[i], cnt = deg[i];
  for (int c0 = 0; c0 < cnt; c0 += 128){
    int m = cnt - c0; if (m > 128) m = 128;
    if (t < m){
      int s = csr_src[start + c0 + t];
      ssrc[t] = s; scoef[t] = dinv[s]*di;
    }
    __syncthreads();
    for (int j = 0; j < m; j++)
      acc += scoef[j] * x4[ssrc[j]*128 + t];
    __syncthreads();
  }
  us4 o; o.x = f2bf(acc.x); o.y = f2bf(acc.y); o.z = f2bf(acc.z); o.w = f2bf(acc.w);
  *(us4*)(Pb + (size_t)i*D_IN + t*4) = o;
}

// ---------------- weight prep ----------------
__global__ void k_transposeW1(const float* __restrict__ W1, unsigned short* __restrict__ Wt1){
  __shared__ float tile[32][33];
  const int n0 = blockIdx.x*32, k0 = blockIdx.y*32;
  const int tx = threadIdx.x, ty = threadIdx.y;    // 32 x 8
  for (int i = 0; i < 32; i += 8)
    tile[ty+i][tx] = W1[(size_t)(k0+ty+i)*D_HID + n0+tx];
  __syncthreads();
  for (int i = 0; i < 32; i += 8)
    Wt1[(size_t)(n0+ty+i)*D_IN + k0+tx] = f2bf(tile[tx][ty+i]);
}

__global__ void k_convW2(const float* __restrict__ W2, unsigned short* __restrict__ Wt2){
  int idx = blockIdx.x*256 + threadIdx.x;          // over 48*2048, layout [n][k]
  if (idx < 48*D_HID){
    int n = idx >> 11, k = idx & (D_HID-1);
    Wt2[idx] = (n < N_CLS) ? f2bf(W2[k*N_CLS + n]) : (unsigned short)0;
  }
}

// ---------------- GEMM1: H1 = relu(Pb @ W1 + b1), bf16 out ----------------
__global__ __launch_bounds__(256) void k_gemm1(const unsigned short* __restrict__ Pb,
                                               const unsigned short* __restrict__ Wt1,
                                               const float* __restrict__ b1,
                                               unsigned short* __restrict__ H1){
  __shared__ short As[128*32];
  __shared__ short Bs[128*32];
  const int t    = threadIdx.x;
  const int lane = t & 63;
  const int wid  = t >> 6;
  const int wm   = (wid >> 1)*64, wn = (wid & 1)*64;
  const int m0   = blockIdx.x*128, n0 = blockIdx.y*128;
  const int arow = t >> 2;            // 0..63
  const int akof = (t & 3)*8;         // bf16 elems
  const int fr   = lane & 15;
  const int fq8  = (lane >> 4)*8;
  const int fq   = lane >> 4;
  f32x4 acc[4][4] = {};
  for (int kb = 0; kb < D_IN; kb += 32){
    gl_lds16(Pb  + (size_t)(m0 +      arow)*D_IN + kb + akof, As + t*8);
    gl_lds16(Pb  + (size_t)(m0 + 64 + arow)*D_IN + kb + akof, As + 2048 + t*8);
    gl_lds16(Wt1 + (size_t)(n0 +      arow)*D_IN + kb + akof, Bs + t*8);
    gl_lds16(Wt1 + (size_t)(n0 + 64 + arow)*D_IN + kb + akof, Bs + 2048 + t*8);
    __syncthreads();
    bf16x8 a[4], b[4];
    #pragma unroll
    for (int i = 0; i < 4; i++) a[i] = *(const bf16x8*)(As + (wm + i*16 + fr)*32 + fq8);
    #pragma unroll
    for (int j = 0; j < 4; j++) b[j] = *(const bf16x8*)(Bs + (wn + j*16 + fr)*32 + fq8);
    #pragma unroll
    for (int i = 0; i < 4; i++)
      #pragma unroll
      for (int j = 0; j < 4; j++)
        acc[i][j] = __builtin_amdgcn_mfma_f32_16x16x32_bf16(a[i], b[j], acc[i][j], 0, 0, 0);
    __syncthreads();
  }
  #pragma unroll
  for (int j = 0; j < 4; j++){
    int col = n0 + wn + j*16 + fr;
    float bias = b1[col];
    #pragma unroll
    for (int i = 0; i < 4; i++){
      int rbase = m0 + wm + i*16 + fq*4;
      f32x4 v = acc[i][j];
      #pragma unroll
      for (int r = 0; r < 4; r++){
        int row = rbase + r;
        if (row < N_NODES){
          float h = fmaxf(v[r] + bias, 0.0f);
          H1[(size_t)row*D_HID + col] = f2bf(h);
        }
      }
    }
  }
}

// ---------------- GEMM2: G = H1 @ W2 (split-K across 4 waves, atomic) ----------------
__global__ __launch_bounds__(256) void k_gemm2(const unsigned short* __restrict__ H1,
                                               const unsigned short* __restrict__ Wt2,
                                               float* __restrict__ G){
  __shared__ short As[4][64*32];
  __shared__ short Bs[4][48*32];
  const int t    = threadIdx.x;
  const int lane = t & 63;
  const int wid  = t >> 6;
  const int m0   = blockIdx.x*64;
  const int lrow = lane >> 2;          // 0..15
  const int lkof = (lane & 3)*8;
  const int fr   = lane & 15;
  const int fq8  = (lane >> 4)*8;
  const int fq   = lane >> 4;
  f32x4 acc[4][3] = {};
  for (int it = 0; it < 16; it++){
    const int kb = wid*512 + it*32;    // each wave owns a K quarter
    #pragma unroll
    for (int c = 0; c < 4; c++)
      gl_lds16(H1 + (size_t)(m0 + c*16 + lrow)*D_HID + kb + lkof, &As[wid][c*512 + lane*8]);
    #pragma unroll
    for (int c = 0; c < 3; c++)
      gl_lds16(Wt2 + (size_t)(c*16 + lrow)*D_HID + kb + lkof, &Bs[wid][c*512 + lane*8]);
    __syncthreads();
    bf16x8 a[4], b[3];
    #pragma unroll
    for (int i = 0; i < 4; i++) a[i] = *(const bf16x8*)(&As[wid][(i*16 + fr)*32 + fq8]);
    #pragma unroll
    for (int j = 0; j < 3; j++) b[j] = *(const bf16x8*)(&Bs[wid][(j*16 + fr)*32 + fq8]);
    #pragma unroll
    for (int i = 0; i < 4; i++)
      #pragma unroll
      for (int j = 0; j < 3; j++)
        acc[i][j] = __builtin_amdgcn_mfma_f32_16x16x32_bf16(a[i], b[j], acc[i][j], 0, 0, 0);
    __syncthreads();
  }
  #pragma unroll
  for (int j = 0; j < 3; j++){
    int col = j*16 + fr;
    #pragma unroll
    for (int i = 0; i < 4; i++){
      int rbase = m0 + i*16 + fq*4;
      f32x4 v = acc[i][j];
      #pragma unroll
      for (int r = 0; r < 4; r++){
        int row = rbase + r;
        if (row < N_NODES && col < N_CLS)
          atomicAdd(&G[row*N_CLS + col], v[r]);
      }
    }
  }
}

// ---------------- propagate(G) + b2 -> out ----------------
__global__ void k_gather2(const float* __restrict__ G, const int* __restrict__ csr_src,
                          const int* __restrict__ offsets, const int* __restrict__ deg,
                          const float* __restrict__ dinv, const float* __restrict__ b2,
                          float* __restrict__ out){
  __shared__ int   ssrc[64];
  __shared__ float scoef[64];
  const int i = blockIdx.x;
  const int t = threadIdx.x;            // 64 threads, 40 active on features
  const float di = dinv[i];
  const int start = offsets[i], cnt = deg[i];
  float acc = 0.0f;
  if (t < N_CLS) acc = di*di * G[i*N_CLS + t];
  for (int c0 = 0; c0 < cnt; c0 += 64){
    int m = cnt - c0; if (m > 64) m = 64;
    if (t < m){
      int s = csr_src[start + c0 + t];
      ssrc[t] = s; scoef[t] = dinv[s]*di;
    }
    __syncthreads();
    if (t < N_CLS)
      for (int j = 0; j < m; j++)
        acc += scoef[j] * G[ssrc[j]*N_CLS + t];
    __syncthreads();
  }
  if (t < N_CLS) out[i*N_CLS + t] = acc + b2[t];
}

extern "C" void kernel_launch(void* const* d_in, const int* in_sizes, int n_in,
                              void* d_out, int out_size, void* d_ws, size_t ws_size,
                              hipStream_t stream){
  const float* x  = (const float*)d_in[0];
  const int*   ei = (const int*)d_in[1];
  const float* W1 = (const float*)d_in[2];
  const float* b1 = (const float*)d_in[3];
  const float* W2 = (const float*)d_in[4];
  const float* b2 = (const float*)d_in[5];
  float* out = (float*)d_out;

  char* ws = (char*)d_ws;
  size_t off = 0;
  auto alloc = [&](size_t bytes) -> void* {
    void* p = ws + off; off += (bytes + 255) & ~(size_t)255; return p;
  };
  int*   deg     = (int*)alloc((size_t)N_NODES*4);
  float* dinv    = (float*)alloc((size_t)N_NODES*4);
  int*   offsets = (int*)alloc((size_t)N_NODES*4);
  int*   cursor  = (int*)alloc((size_t)N_NODES*4);
  int*   csr     = (int*)alloc((size_t)N_EDGES*4);
  unsigned short* Pb  = (unsigned short*)alloc((size_t)MP1*D_IN*2);
  unsigned short* Wt1 = (unsigned short*)alloc((size_t)D_HID*D_IN*2);
  unsigned short* Wt2 = (unsigned short*)alloc((size_t)48*D_HID*2);
  unsigned short* H1  = (unsigned short*)alloc((size_t)MP1*D_HID*2);
  float* G = (float*)alloc((size_t)N_NODES*N_CLS*4);

  hipMemsetAsync(deg, 0, (size_t)N_NODES*4, stream);
  hipMemsetAsync(G,   0, (size_t)N_NODES*N_CLS*4, stream);

  k_count<<<(N_EDGES+255)/256, 256, 0, stream>>>(ei, deg);
  k_dinv<<<(N_NODES+255)/256, 256, 0, stream>>>(deg, dinv);
  k_scan<<<1, 1024, 0, stream>>>(deg, offsets, cursor);
  k_fill<<<(N_EDGES+255)/256, 256, 0, stream>>>(ei, cursor, csr);
  k_gather1<<<N_NODES, 128, 0, stream>>>(x, csr, offsets, deg, dinv, Pb);
  k_transposeW1<<<dim3(D_HID/32, D_IN/32), dim3(32,8), 0, stream>>>(W1, Wt1);
  k_convW2<<<(48*D_HID+255)/256, 256, 0, stream>>>(W2, Wt2);
  k_gemm1<<<dim3(MP1/128, D_HID/128), 256, 0, stream>>>(Pb, Wt1, b1, H1);
  k_gemm2<<<(N_NODES+63)/64, 256, 0, stream>>>(H1, Wt2, G);
  k_gather2<<<N_NODES, 64, 0, stream>>>(G, csr, offsets, deg, dinv, b2, out);
}

// Round 2
// 271.053 us; speedup vs baseline: 1.1040x; 1.1040x over previous
//
#include <hip/hip_runtime.h>
#include <stdint.h>

#define N_NODES 10000
#define N_EDGES 320000
#define D_IN    512
#define D_HID   2048
#define N_CLS   40
#define MP1     10112   // 79*128  (GEMM1 M padding)

typedef float f32x4  __attribute__((ext_vector_type(4)));
typedef short bf16x8 __attribute__((ext_vector_type(8)));
typedef unsigned short us4 __attribute__((ext_vector_type(4)));
typedef unsigned short us8 __attribute__((ext_vector_type(8)));

__device__ inline unsigned short f2bf(float f){
  unsigned int u = __float_as_uint(f);
  u += 0x7fffu + ((u >> 16) & 1u);   // round-to-nearest-even
  return (unsigned short)(u >> 16);
}

__device__ inline float bf2f(unsigned short h){
  return __uint_as_float(((unsigned int)h) << 16);
}

__device__ inline void gl_lds16(const void* g, void* l){
  __builtin_amdgcn_global_load_lds((const __attribute__((address_space(1))) void*)g,
                                   (__attribute__((address_space(3))) void*)l, 16, 0, 0);
}

// ---------------- graph preprocessing ----------------
__global__ void k_count(const int* __restrict__ ei, int* __restrict__ deg){
  int e = blockIdx.x*256 + threadIdx.x;
  if (e < N_EDGES) atomicAdd(&deg[ei[N_EDGES + e]], 1);
}

// exclusive scan of deg -> offsets/cursor, plus dinv = rsqrt(deg+1)
__global__ void k_scan(const int* __restrict__ deg, int* __restrict__ offsets,
                       int* __restrict__ cursor, float* __restrict__ dinv){
  __shared__ int sums[1024];
  const int t = threadIdx.x;
  const int CH = 10;                       // 1024*10 >= 10000
  int base = t*CH;
  int local[CH]; int s = 0;
  for (int j = 0; j < CH; j++){
    int v = (base + j < N_NODES) ? deg[base + j] : 0;
    local[j] = s; s += v;
    if (base + j < N_NODES) dinv[base + j] = rsqrtf((float)v + 1.0f);
  }
  sums[t] = s;
  __syncthreads();
  for (int off = 1; off < 1024; off <<= 1){
    int v = (t >= off) ? sums[t - off] : 0;
    __syncthreads();
    sums[t] += v;
    __syncthreads();
  }
  int pre = (t > 0) ? sums[t-1] : 0;
  for (int j = 0; j < CH; j++){
    int idx = base + j;
    if (idx < N_NODES){ int o = pre + local[j]; offsets[idx] = o; cursor[idx] = o; }
  }
}

__global__ void k_fill(const int* __restrict__ ei, int* __restrict__ cursor, int* __restrict__ csr_src){
  int e = blockIdx.x*256 + threadIdx.x;
  if (e < N_EDGES){
    int s = ei[e], d = ei[N_EDGES + e];
    int pos = atomicAdd(&cursor[d], 1);
    csr_src[pos] = s;
  }
}

// ---------------- x -> bf16 ----------------
__global__ void k_castx(const float* __restrict__ x, unsigned short* __restrict__ Xb){
  int idx = blockIdx.x*256 + threadIdx.x;   // each handles 8 elems
  const f32x4* x4 = (const f32x4*)x;
  f32x4 a = x4[idx*2], b = x4[idx*2+1];
  us8 o;
  o[0]=f2bf(a.x); o[1]=f2bf(a.y); o[2]=f2bf(a.z); o[3]=f2bf(a.w);
  o[4]=f2bf(b.x); o[5]=f2bf(b.y); o[6]=f2bf(b.z); o[7]=f2bf(b.w);
  *(us8*)(Xb + (size_t)idx*8) = o;
}

// ---------------- propagate(Xb) -> Pb (bf16), one wave per node ----------------
__global__ __launch_bounds__(256) void k_gather1(const unsigned short* __restrict__ Xb,
                          const int* __restrict__ csr_src,
                          const int* __restrict__ offsets, const int* __restrict__ deg,
                          const float* __restrict__ dinv, unsigned short* __restrict__ Pb){
  const int w    = threadIdx.x >> 6;
  const int lane = threadIdx.x & 63;
  const int i    = blockIdx.x*4 + w;       // 2500 blocks x 4 waves = 10000 nodes
  const float di = dinv[i];
  float acc[8];
  us8 xi = *(const us8*)(Xb + (size_t)i*D_IN + lane*8);
  const float dii = di*di;
  #pragma unroll
  for (int r = 0; r < 8; r++) acc[r] = dii * bf2f(xi[r]);
  const int start = offsets[i], cnt = deg[i];
  for (int c0 = 0; c0 < cnt; c0 += 64){
    int m = cnt - c0; if (m > 64) m = 64;
    int s = 0; float cf = 0.0f;
    if (lane < m){ s = csr_src[start + c0 + lane]; cf = dinv[s]*di; }
    for (int j = 0; j < m; j++){           // wave-uniform trip count
      int   sj = __shfl(s, j);
      float cj = __shfl(cf, j);
      us8 xr = *(const us8*)(Xb + (size_t)sj*D_IN + lane*8);
      #pragma unroll
      for (int r = 0; r < 8; r++) acc[r] += cj * bf2f(xr[r]);
    }
  }
  us8 o;
  #pragma unroll
  for (int r = 0; r < 8; r++) o[r] = f2bf(acc[r]);
  *(us8*)(Pb + (size_t)i*D_IN + lane*8) = o;
}

// ---------------- weight prep ----------------
__global__ void k_transposeW1(const float* __restrict__ W1, unsigned short* __restrict__ Wt1){
  __shared__ float tile[32][33];
  const int n0 = blockIdx.x*32, k0 = blockIdx.y*32;
  const int tx = threadIdx.x, ty = threadIdx.y;    // 32 x 8
  for (int i = 0; i < 32; i += 8)
    tile[ty+i][tx] = W1[(size_t)(k0+ty+i)*D_HID + n0+tx];
  __syncthreads();
  for (int i = 0; i < 32; i += 8)
    Wt1[(size_t)(n0+ty+i)*D_IN + k0+tx] = f2bf(tile[tx][ty+i]);
}

__global__ void k_convW2(const float* __restrict__ W2, unsigned short* __restrict__ Wt2){
  int idx = blockIdx.x*256 + threadIdx.x;          // over 48*2048, layout [n][k]
  if (idx < 48*D_HID){
    int n = idx >> 11, k = idx & (D_HID-1);
    Wt2[idx] = (n < N_CLS) ? f2bf(W2[k*N_CLS + n]) : (unsigned short)0;
  }
}

// ---------------- GEMM1: H1 = relu(Pb @ W1 + b1), bf16 out ----------------
__global__ __launch_bounds__(256) void k_gemm1(const unsigned short* __restrict__ Pb,
                                               const unsigned short* __restrict__ Wt1,
                                               const float* __restrict__ b1,
                                               unsigned short* __restrict__ H1){
  __shared__ short As[128*32];
  __shared__ short Bs[128*32];
  const int t    = threadIdx.x;
  const int lane = t & 63;
  const int wid  = t >> 6;
  const int wm   = (wid >> 1)*64, wn = (wid & 1)*64;
  const int m0   = blockIdx.x*128, n0 = blockIdx.y*128;
  const int arow = t >> 2;            // 0..63
  const int akof = (t & 3)*8;         // bf16 elems
  const int fr   = lane & 15;
  const int fq8  = (lane >> 4)*8;
  const int fq   = lane >> 4;
  f32x4 acc[4][4] = {};
  for (int kb = 0; kb < D_IN; kb += 32){
    gl_lds16(Pb  + (size_t)(m0 +      arow)*D_IN + kb + akof, As + t*8);
    gl_lds16(Pb  + (size_t)(m0 + 64 + arow)*D_IN + kb + akof, As + 2048 + t*8);
    gl_lds16(Wt1 + (size_t)(n0 +      arow)*D_IN + kb + akof, Bs + t*8);
    gl_lds16(Wt1 + (size_t)(n0 + 64 + arow)*D_IN + kb + akof, Bs + 2048 + t*8);
    __syncthreads();
    bf16x8 a[4], b[4];
    #pragma unroll
    for (int i = 0; i < 4; i++) a[i] = *(const bf16x8*)(As + (wm + i*16 + fr)*32 + fq8);
    #pragma unroll
    for (int j = 0; j < 4; j++) b[j] = *(const bf16x8*)(Bs + (wn + j*16 + fr)*32 + fq8);
    #pragma unroll
    for (int i = 0; i < 4; i++)
      #pragma unroll
      for (int j = 0; j < 4; j++)
        acc[i][j] = __builtin_amdgcn_mfma_f32_16x16x32_bf16(a[i], b[j], acc[i][j], 0, 0, 0);
    __syncthreads();
  }
  #pragma unroll
  for (int j = 0; j < 4; j++){
    int col = n0 + wn + j*16 + fr;
    float bias = b1[col];
    #pragma unroll
    for (int i = 0; i < 4; i++){
      int rbase = m0 + wm + i*16 + fq*4;
      f32x4 v = acc[i][j];
      #pragma unroll
      for (int r = 0; r < 4; r++){
        int row = rbase + r;
        if (row < N_NODES){
          float h = fmaxf(v[r] + bias, 0.0f);
          H1[(size_t)row*D_HID + col] = f2bf(h);
        }
      }
    }
  }
}

// ---------------- GEMM2: G = H1 @ W2 (split-K across 4 waves, atomic) ----------------
__global__ __launch_bounds__(256) void k_gemm2(const unsigned short* __restrict__ H1,
                                               const unsigned short* __restrict__ Wt2,
                                               float* __restrict__ G){
  __shared__ short As[4][64*32];
  __shared__ short Bs[4][48*32];
  const int t    = threadIdx.x;
  const int lane = t & 63;
  const int wid  = t >> 6;
  const int m0   = blockIdx.x*64;
  const int lrow = lane >> 2;          // 0..15
  const int lkof = (lane & 3)*8;
  const int fr   = lane & 15;
  const int fq8  = (lane >> 4)*8;
  const int fq   = lane >> 4;
  f32x4 acc[4][3] = {};
  for (int it = 0; it < 16; it++){
    const int kb = wid*512 + it*32;    // each wave owns a K quarter
    #pragma unroll
    for (int c = 0; c < 4; c++)
      gl_lds16(H1 + (size_t)(m0 + c*16 + lrow)*D_HID + kb + lkof, &As[wid][c*512 + lane*8]);
    #pragma unroll
    for (int c = 0; c < 3; c++)
      gl_lds16(Wt2 + (size_t)(c*16 + lrow)*D_HID + kb + lkof, &Bs[wid][c*512 + lane*8]);
    __syncthreads();
    bf16x8 a[4], b[3];
    #pragma unroll
    for (int i = 0; i < 4; i++) a[i] = *(const bf16x8*)(&As[wid][(i*16 + fr)*32 + fq8]);
    #pragma unroll
    for (int j = 0; j < 3; j++) b[j] = *(const bf16x8*)(&Bs[wid][(j*16 + fr)*32 + fq8]);
    #pragma unroll
    for (int i = 0; i < 4; i++)
      #pragma unroll
      for (int j = 0; j < 3; j++)
        acc[i][j] = __builtin_amdgcn_mfma_f32_16x16x32_bf16(a[i], b[j], acc[i][j], 0, 0, 0);
    __syncthreads();
  }
  #pragma unroll
  for (int j = 0; j < 3; j++){
    int col = j*16 + fr;
    #pragma unroll
    for (int i = 0; i < 4; i++){
      int rbase = m0 + i*16 + fq*4;
      f32x4 v = acc[i][j];
      #pragma unroll
      for (int r = 0; r < 4; r++){
        int row = rbase + r;
        if (row < N_NODES && col < N_CLS)
          atomicAdd(&G[row*N_CLS + col], v[r]);
      }
    }
  }
}

// ---------------- propagate(G) + b2 -> out ----------------
__global__ void k_gather2(const float* __restrict__ G, const int* __restrict__ csr_src,
                          const int* __restrict__ offsets, const int* __restrict__ deg,
                          const float* __restrict__ dinv, const float* __restrict__ b2,
                          float* __restrict__ out){
  __shared__ int   ssrc[64];
  __shared__ float scoef[64];
  const int i = blockIdx.x;
  const int t = threadIdx.x;            // 64 threads, 40 active on features
  const float di = dinv[i];
  const int start = offsets[i], cnt = deg[i];
  float acc = 0.0f;
  if (t < N_CLS) acc = di*di * G[i*N_CLS + t];
  for (int c0 = 0; c0 < cnt; c0 += 64){
    int m = cnt - c0; if (m > 64) m = 64;
    if (t < m){
      int s = csr_src[start + c0 + t];
      ssrc[t] = s; scoef[t] = dinv[s]*di;
    }
    __syncthreads();
    if (t < N_CLS)
      for (int j = 0; j < m; j++)
        acc += scoef[j] * G[ssrc[j]*N_CLS + t];
    __syncthreads();
  }
  if (t < N_CLS) out[i*N_CLS + t] = acc + b2[t];
}

extern "C" void kernel_launch(void* const* d_in, const int* in_sizes, int n_in,
                              void* d_out, int out_size, void* d_ws, size_t ws_size,
                              hipStream_t stream){
  const float* x  = (const float*)d_in[0];
  const int*   ei = (const int*)d_in[1];
  const float* W1 = (const float*)d_in[2];
  const float* b1 = (const float*)d_in[3];
  const float* W2 = (const float*)d_in[4];
  const float* b2 = (const float*)d_in[5];
  float* out = (float*)d_out;

  char* ws = (char*)d_ws;
  size_t off = 0;
  auto alloc = [&](size_t bytes) -> void* {
    void* p = ws + off; off += (bytes + 255) & ~(size_t)255; return p;
  };
  int*   deg     = (int*)alloc((size_t)N_NODES*4);
  float* dinv    = (float*)alloc((size_t)N_NODES*4);
  int*   offsets = (int*)alloc((size_t)N_NODES*4);
  int*   cursor  = (int*)alloc((size_t)N_NODES*4);
  int*   csr     = (int*)alloc((size_t)N_EDGES*4);
  unsigned short* Xb  = (unsigned short*)alloc((size_t)N_NODES*D_IN*2);
  unsigned short* Pb  = (unsigned short*)alloc((size_t)MP1*D_IN*2);
  unsigned short* Wt1 = (unsigned short*)alloc((size_t)D_HID*D_IN*2);
  unsigned short* Wt2 = (unsigned short*)alloc((size_t)48*D_HID*2);
  unsigned short* H1  = (unsigned short*)alloc((size_t)MP1*D_HID*2);
  float* G = (float*)alloc((size_t)N_NODES*N_CLS*4);

  hipMemsetAsync(deg, 0, (size_t)N_NODES*4, stream);
  hipMemsetAsync(G,   0, (size_t)N_NODES*N_CLS*4, stream);

  k_count<<<(N_EDGES+255)/256, 256, 0, stream>>>(ei, deg);
  k_scan<<<1, 1024, 0, stream>>>(deg, offsets, cursor, dinv);
  k_fill<<<(N_EDGES+255)/256, 256, 0, stream>>>(ei, cursor, csr);
  k_castx<<<(N_NODES*D_IN/8 + 255)/256, 256, 0, stream>>>(x, Xb);
  k_gather1<<<N_NODES/4, 256, 0, stream>>>(Xb, csr, offsets, deg, dinv, Pb);
  k_transposeW1<<<dim3(D_HID/32, D_IN/32), dim3(32,8), 0, stream>>>(W1, Wt1);
  k_convW2<<<(48*D_HID+255)/256, 256, 0, stream>>>(W2, Wt2);
  k_gemm1<<<dim3(MP1/128, D_HID/128), 256, 0, stream>>>(Pb, Wt1, b1, H1);
  k_gemm2<<<(N_NODES+63)/64, 256, 0, stream>>>(H1, Wt2, G);
  k_gather2<<<N_NODES, 64, 0, stream>>>(G, csr, offsets, deg, dinv, b2, out);
}

// Round 3
// 267.774 us; speedup vs baseline: 1.1176x; 1.0122x over previous
//
#include <hip/hip_runtime.h>
#include <stdint.h>

#define N_NODES 10000
#define N_EDGES 320000
#define D_IN    512
#define D_HID   2048
#define N_CLS   40
#define MP1     10112   // 79*128  (GEMM1 M padding)

typedef float f32x4  __attribute__((ext_vector_type(4)));
typedef short bf16x8 __attribute__((ext_vector_type(8)));
typedef unsigned short us4 __attribute__((ext_vector_type(4)));
typedef unsigned short us8 __attribute__((ext_vector_type(8)));

__device__ inline unsigned short f2bf(float f){
  unsigned int u = __float_as_uint(f);
  u += 0x7fffu + ((u >> 16) & 1u);   // round-to-nearest-even
  return (unsigned short)(u >> 16);
}

__device__ inline float bf2f(unsigned short h){
  return __uint_as_float(((unsigned int)h) << 16);
}

__device__ inline void gl_lds16(const void* g, void* l){
  __builtin_amdgcn_global_load_lds((const __attribute__((address_space(1))) void*)g,
                                   (__attribute__((address_space(3))) void*)l, 16, 0, 0);
}

// ---------------- graph preprocessing ----------------
__global__ void k_count(const int* __restrict__ ei, int* __restrict__ deg){
  int e = blockIdx.x*256 + threadIdx.x;
  if (e < N_EDGES) atomicAdd(&deg[ei[N_EDGES + e]], 1);
}

// exclusive scan of deg -> offsets/cursor, plus dinv = rsqrt(deg+1)
__global__ void k_scan(const int* __restrict__ deg, int* __restrict__ offsets,
                       int* __restrict__ cursor, float* __restrict__ dinv){
  __shared__ int sums[1024];
  const int t = threadIdx.x;
  const int CH = 10;                       // 1024*10 >= 10000
  int base = t*CH;
  int local[CH]; int s = 0;
  for (int j = 0; j < CH; j++){
    int v = (base + j < N_NODES) ? deg[base + j] : 0;
    local[j] = s; s += v;
    if (base + j < N_NODES) dinv[base + j] = rsqrtf((float)v + 1.0f);
  }
  sums[t] = s;
  __syncthreads();
  for (int off = 1; off < 1024; off <<= 1){
    int v = (t >= off) ? sums[t - off] : 0;
    __syncthreads();
    sums[t] += v;
    __syncthreads();
  }
  int pre = (t > 0) ? sums[t-1] : 0;
  for (int j = 0; j < CH; j++){
    int idx = base + j;
    if (idx < N_NODES){ int o = pre + local[j]; offsets[idx] = o; cursor[idx] = o; }
  }
}

__global__ void k_fill(const int* __restrict__ ei, int* __restrict__ cursor, int* __restrict__ csr_src){
  int e = blockIdx.x*256 + threadIdx.x;
  if (e < N_EDGES){
    int s = ei[e], d = ei[N_EDGES + e];
    int pos = atomicAdd(&cursor[d], 1);
    csr_src[pos] = s;
  }
}

// ---------------- x -> bf16 ----------------
__global__ void k_castx(const float* __restrict__ x, unsigned short* __restrict__ Xb){
  int idx = blockIdx.x*256 + threadIdx.x;   // each handles 8 elems
  const f32x4* x4 = (const f32x4*)x;
  f32x4 a = x4[idx*2], b = x4[idx*2+1];
  us8 o;
  o[0]=f2bf(a.x); o[1]=f2bf(a.y); o[2]=f2bf(a.z); o[3]=f2bf(a.w);
  o[4]=f2bf(b.x); o[5]=f2bf(b.y); o[6]=f2bf(b.z); o[7]=f2bf(b.w);
  *(us8*)(Xb + (size_t)idx*8) = o;
}

// ---------------- propagate(Xb) -> Pb (bf16), one wave per node ----------------
__global__ __launch_bounds__(256) void k_gather1(const unsigned short* __restrict__ Xb,
                          const int* __restrict__ csr_src,
                          const int* __restrict__ offsets, const int* __restrict__ deg,
                          const float* __restrict__ dinv, unsigned short* __restrict__ Pb){
  const int w    = threadIdx.x >> 6;
  const int lane = threadIdx.x & 63;
  const int i    = blockIdx.x*4 + w;       // 2500 blocks x 4 waves = 10000 nodes
  const float di = dinv[i];
  float acc[8];
  us8 xi = *(const us8*)(Xb + (size_t)i*D_IN + lane*8);
  const float dii = di*di;
  #pragma unroll
  for (int r = 0; r < 8; r++) acc[r] = dii * bf2f(xi[r]);
  const int start = offsets[i], cnt = deg[i];
  for (int c0 = 0; c0 < cnt; c0 += 64){
    int m = cnt - c0; if (m > 64) m = 64;
    int s = 0; float cf = 0.0f;
    if (lane < m){ s = csr_src[start + c0 + lane]; cf = dinv[s]*di; }
    for (int j = 0; j < m; j++){           // wave-uniform trip count
      int   sj = __shfl(s, j);
      float cj = __shfl(cf, j);
      us8 xr = *(const us8*)(Xb + (size_t)sj*D_IN + lane*8);
      #pragma unroll
      for (int r = 0; r < 8; r++) acc[r] += cj * bf2f(xr[r]);
    }
  }
  us8 o;
  #pragma unroll
  for (int r = 0; r < 8; r++) o[r] = f2bf(acc[r]);
  *(us8*)(Pb + (size_t)i*D_IN + lane*8) = o;
}

// ---------------- weight prep ----------------
__global__ void k_transposeW1(const float* __restrict__ W1, unsigned short* __restrict__ Wt1){
  __shared__ float tile[32][33];
  const int n0 = blockIdx.x*32, k0 = blockIdx.y*32;
  const int tx = threadIdx.x, ty = threadIdx.y;    // 32 x 8
  for (int i = 0; i < 32; i += 8)
    tile[ty+i][tx] = W1[(size_t)(k0+ty+i)*D_HID + n0+tx];
  __syncthreads();
  for (int i = 0; i < 32; i += 8)
    Wt1[(size_t)(n0+ty+i)*D_IN + k0+tx] = f2bf(tile[tx][ty+i]);
}

__global__ void k_convW2(const float* __restrict__ W2, unsigned short* __restrict__ Wt2){
  int idx = blockIdx.x*256 + threadIdx.x;          // over 48*2048, layout [n][k]
  if (idx < 48*D_HID){
    int n = idx >> 11, k = idx & (D_HID-1);
    Wt2[idx] = (n < N_CLS) ? f2bf(W2[k*N_CLS + n]) : (unsigned short)0;
  }
}

// ---------------- GEMM1: H1 = relu(Pb @ W1 + b1), bf16 out ----------------
// LDS layout swizzle (bank-conflict fix): chunk q (8 bf16) of row r lives at
// byte offset r*64 + (q ^ ((r>>1)&3))*16. Staging lane fetches the matching
// global chunk so global_load_lds's fixed dest (base + lane*16) lands right.
__global__ __launch_bounds__(256) void k_gemm1(const unsigned short* __restrict__ Pb,
                                               const unsigned short* __restrict__ Wt1,
                                               const float* __restrict__ b1,
                                               unsigned short* __restrict__ H1){
  __shared__ short As[128*32];
  __shared__ short Bs[128*32];
  const int t    = threadIdx.x;
  const int lane = t & 63;
  const int wid  = t >> 6;
  const int wm   = (wid >> 1)*64, wn = (wid & 1)*64;
  const int m0   = blockIdx.x*128, n0 = blockIdx.y*128;
  const int arow = t >> 2;                        // 0..63
  const int akof = ((t & 3) ^ ((t >> 3) & 3))*8;  // swizzled source chunk
  const int fr   = lane & 15;
  const int q    = lane >> 4;
  const int sq8  = (q ^ ((fr >> 1) & 3))*8;       // swizzled read offset
  const int fq   = lane >> 4;
  f32x4 acc[4][4] = {};
  for (int kb = 0; kb < D_IN; kb += 32){
    gl_lds16(Pb  + (size_t)(m0 +      arow)*D_IN + kb + akof, As + t*8);
    gl_lds16(Pb  + (size_t)(m0 + 64 + arow)*D_IN + kb + akof, As + 2048 + t*8);
    gl_lds16(Wt1 + (size_t)(n0 +      arow)*D_IN + kb + akof, Bs + t*8);
    gl_lds16(Wt1 + (size_t)(n0 + 64 + arow)*D_IN + kb + akof, Bs + 2048 + t*8);
    __syncthreads();
    bf16x8 a[4], b[4];
    #pragma unroll
    for (int i = 0; i < 4; i++) a[i] = *(const bf16x8*)(As + (wm + i*16 + fr)*32 + sq8);
    #pragma unroll
    for (int j = 0; j < 4; j++) b[j] = *(const bf16x8*)(Bs + (wn + j*16 + fr)*32 + sq8);
    #pragma unroll
    for (int i = 0; i < 4; i++)
      #pragma unroll
      for (int j = 0; j < 4; j++)
        acc[i][j] = __builtin_amdgcn_mfma_f32_16x16x32_bf16(a[i], b[j], acc[i][j], 0, 0, 0);
    __syncthreads();
  }
  #pragma unroll
  for (int j = 0; j < 4; j++){
    int col = n0 + wn + j*16 + fr;
    float bias = b1[col];
    #pragma unroll
    for (int i = 0; i < 4; i++){
      int rbase = m0 + wm + i*16 + fq*4;
      f32x4 v = acc[i][j];
      #pragma unroll
      for (int r = 0; r < 4; r++){
        int row = rbase + r;
        if (row < N_NODES){
          float h = fmaxf(v[r] + bias, 0.0f);
          H1[(size_t)row*D_HID + col] = f2bf(h);
        }
      }
    }
  }
}

// ---------------- GEMM2: G = H1 @ W2 (split-K across 4 waves, atomic) ----------------
__global__ __launch_bounds__(256) void k_gemm2(const unsigned short* __restrict__ H1,
                                               const unsigned short* __restrict__ Wt2,
                                               float* __restrict__ G){
  __shared__ short As[4][64*32];
  __shared__ short Bs[4][48*32];
  const int t    = threadIdx.x;
  const int lane = t & 63;
  const int wid  = t >> 6;
  const int m0   = blockIdx.x*64;
  const int lrow = lane >> 2;                           // 0..15
  const int lkof = ((lane & 3) ^ ((lane >> 3) & 3))*8;  // swizzled source chunk
  const int fr   = lane & 15;
  const int sq8  = ((lane >> 4) ^ ((fr >> 1) & 3))*8;   // swizzled read offset
  const int fq   = lane >> 4;
  f32x4 acc[4][3] = {};
  for (int it = 0; it < 16; it++){
    const int kb = wid*512 + it*32;    // each wave owns a K quarter
    #pragma unroll
    for (int c = 0; c < 4; c++)
      gl_lds16(H1 + (size_t)(m0 + c*16 + lrow)*D_HID + kb + lkof, &As[wid][c*512 + lane*8]);
    #pragma unroll
    for (int c = 0; c < 3; c++)
      gl_lds16(Wt2 + (size_t)(c*16 + lrow)*D_HID + kb + lkof, &Bs[wid][c*512 + lane*8]);
    __syncthreads();
    bf16x8 a[4], b[3];
    #pragma unroll
    for (int i = 0; i < 4; i++) a[i] = *(const bf16x8*)(&As[wid][(i*16 + fr)*32 + sq8]);
    #pragma unroll
    for (int j = 0; j < 3; j++) b[j] = *(const bf16x8*)(&Bs[wid][(j*16 + fr)*32 + sq8]);
    #pragma unroll
    for (int i = 0; i < 4; i++)
      #pragma unroll
      for (int j = 0; j < 3; j++)
        acc[i][j] = __builtin_amdgcn_mfma_f32_16x16x32_bf16(a[i], b[j], acc[i][j], 0, 0, 0);
    __syncthreads();
  }
  #pragma unroll
  for (int j = 0; j < 3; j++){
    int col = j*16 + fr;
    #pragma unroll
    for (int i = 0; i < 4; i++){
      int rbase = m0 + i*16 + fq*4;
      f32x4 v = acc[i][j];
      #pragma unroll
      for (int r = 0; r < 4; r++){
        int row = rbase + r;
        if (row < N_NODES && col < N_CLS)
          atomicAdd(&G[row*N_CLS + col], v[r]);
      }
    }
  }
}

// ---------------- propagate(G) + b2 -> out ----------------
__global__ void k_gather2(const float* __restrict__ G, const int* __restrict__ csr_src,
                          const int* __restrict__ offsets, const int* __restrict__ deg,
                          const float* __restrict__ dinv, const float* __restrict__ b2,
                          float* __restrict__ out){
  __shared__ int   ssrc[64];
  __shared__ float scoef[64];
  const int i = blockIdx.x;
  const int t = threadIdx.x;            // 64 threads, 40 active on features
  const float di = dinv[i];
  const int start = offsets[i], cnt = deg[i];
  float acc = 0.0f;
  if (t < N_CLS) acc = di*di * G[i*N_CLS + t];
  for (int c0 = 0; c0 < cnt; c0 += 64){
    int m = cnt - c0; if (m > 64) m = 64;
    if (t < m){
      int s = csr_src[start + c0 + t];
      ssrc[t] = s; scoef[t] = dinv[s]*di;
    }
    __syncthreads();
    if (t < N_CLS)
      for (int j = 0; j < m; j++)
        acc += scoef[j] * G[ssrc[j]*N_CLS + t];
    __syncthreads();
  }
  if (t < N_CLS) out[i*N_CLS + t] = acc + b2[t];
}

extern "C" void kernel_launch(void* const* d_in, const int* in_sizes, int n_in,
                              void* d_out, int out_size, void* d_ws, size_t ws_size,
                              hipStream_t stream){
  const float* x  = (const float*)d_in[0];
  const int*   ei = (const int*)d_in[1];
  const float* W1 = (const float*)d_in[2];
  const float* b1 = (const float*)d_in[3];
  const float* W2 = (const float*)d_in[4];
  const float* b2 = (const float*)d_in[5];
  float* out = (float*)d_out;

  char* ws = (char*)d_ws;
  size_t off = 0;
  auto alloc = [&](size_t bytes) -> void* {
    void* p = ws + off; off += (bytes + 255) & ~(size_t)255; return p;
  };
  int*   deg     = (int*)alloc((size_t)N_NODES*4);
  float* dinv    = (float*)alloc((size_t)N_NODES*4);
  int*   offsets = (int*)alloc((size_t)N_NODES*4);
  int*   cursor  = (int*)alloc((size_t)N_NODES*4);
  int*   csr     = (int*)alloc((size_t)N_EDGES*4);
  unsigned short* Xb  = (unsigned short*)alloc((size_t)N_NODES*D_IN*2);
  unsigned short* Pb  = (unsigned short*)alloc((size_t)MP1*D_IN*2);
  unsigned short* Wt1 = (unsigned short*)alloc((size_t)D_HID*D_IN*2);
  unsigned short* Wt2 = (unsigned short*)alloc((size_t)48*D_HID*2);
  unsigned short* H1  = (unsigned short*)alloc((size_t)MP1*D_HID*2);
  float* G = (float*)alloc((size_t)N_NODES*N_CLS*4);

  hipMemsetAsync(deg, 0, (size_t)N_NODES*4, stream);
  hipMemsetAsync(G,   0, (size_t)N_NODES*N_CLS*4, stream);

  k_count<<<(N_EDGES+255)/256, 256, 0, stream>>>(ei, deg);
  k_scan<<<1, 1024, 0, stream>>>(deg, offsets, cursor, dinv);
  k_fill<<<(N_EDGES+255)/256, 256, 0, stream>>>(ei, cursor, csr);
  k_castx<<<(N_NODES*D_IN/8 + 255)/256, 256, 0, stream>>>(x, Xb);
  k_gather1<<<N_NODES/4, 256, 0, stream>>>(Xb, csr, offsets, deg, dinv, Pb);
  k_transposeW1<<<dim3(D_HID/32, D_IN/32), dim3(32,8), 0, stream>>>(W1, Wt1);
  k_convW2<<<(48*D_HID+255)/256, 256, 0, stream>>>(W2, Wt2);
  k_gemm1<<<dim3(MP1/128, D_HID/128), 256, 0, stream>>>(Pb, Wt1, b1, H1);
  k_gemm2<<<(N_NODES+63)/64, 256, 0, stream>>>(H1, Wt2, G);
  k_gather2<<<N_NODES, 64, 0, stream>>>(G, csr, offsets, deg, dinv, b2, out);
}